// Round 16
// baseline (184.073 us; speedup 1.0000x reference)
//
#include <hip/hip_runtime.h>
#include <hip/hip_bf16.h>

typedef __attribute__((ext_vector_type(8))) short bf16x8;
typedef __attribute__((ext_vector_type(4))) float f32x4;

__device__ __forceinline__ ushort f2bf(float f) {
    __hip_bfloat16 h = __float2bfloat16(f);
    return __builtin_bit_cast(ushort, h);
}
__device__ __forceinline__ unsigned pack2(float a, float b) {
    return (unsigned)f2bf(a) | ((unsigned)f2bf(b) << 16);
}
__device__ __forceinline__ float bflo(unsigned u) { return __uint_as_float(u << 16); }

// ---------------------------------------------------------------------------
// L1 kvctx: 512 blocks (2/CU), one per (b, n-chunk of 32):
//   kv = w_kv @ cond chunk (BM=256, BN=32, BK=64, K=512, 8 waves) with fused
//   epilogue: bias + exp(k-half) + rowsum partials -> rsp, bf16 tile in LDS,
//   per-head PV contraction (single K=32 MFMA per quadrant) -> ctxp.
//   PLUS GN stats: block (b,nc) owns group (b,nc) x-slice, woven into K-loop.
__global__ __launch_bounds__(512) void kvctx_kernel(const float* __restrict__ w_kv,
                                                    const float* __restrict__ cond,
                                                    const float* __restrict__ b_kv,
                                                    const float* __restrict__ x,
                                                    float* __restrict__ statacc,
                                                    float* __restrict__ rsp,
                                                    float* __restrict__ ctxp) {
    __shared__ ushort lA[256 * 64];     // 32 KB (reused as [256][32] bf16 kv tile)
    __shared__ ushort lB[32 * 64];      // 4 KB
    __shared__ float scratch[64 * 32];  // 8 KB, granule-swizzled
    __shared__ float red2[8][2];
    int bid = blockIdx.x, t = threadIdx.x;
    int b = bid >> 5, nc = bid & 31;
    int col0 = nc * 32;
    int l = t & 63, w = t >> 6;          // wave 0..7, rows w*32..w*32+31
    int lr = l & 15, lg = l >> 4;
    const float* Bb = cond + (size_t)b * 512 * 1024 + col0;
    const float4* xc = (const float4*)(x + (size_t)b * 1048576 + (size_t)nc * 32768);
    int rA = t >> 3, gAr = t & 7, gw = gAr ^ (rA & 7);  // (64m+rA)&7==rA&7
    int rB = t >> 3, gB = t & 7;         // B: row 0..63, granule 0..7 (32 floats/row)
    int sp = t & 31, sj4 = (t >> 5) & 7; // PACKB (t<256): k-pair, n-quad
    float4 ka0_, ka1_, ka2_, ka3_, ka4_, ka5_, ka6_, ka7_;
    float4 kb0_;
    float4 xv0_, xv1_;
    float sA = 0.f, ssA = 0.f;
#define KC_LOADA(k0) { \
    ka0_ = *(const float4*)&w_kv[(size_t)(rA)       * 512 + (k0) + gAr * 8]; \
    ka1_ = *(const float4*)&w_kv[(size_t)(rA)       * 512 + (k0) + gAr * 8 + 4]; \
    ka2_ = *(const float4*)&w_kv[(size_t)(64 + rA)  * 512 + (k0) + gAr * 8]; \
    ka3_ = *(const float4*)&w_kv[(size_t)(64 + rA)  * 512 + (k0) + gAr * 8 + 4]; \
    ka4_ = *(const float4*)&w_kv[(size_t)(128 + rA) * 512 + (k0) + gAr * 8]; \
    ka5_ = *(const float4*)&w_kv[(size_t)(128 + rA) * 512 + (k0) + gAr * 8 + 4]; \
    ka6_ = *(const float4*)&w_kv[(size_t)(192 + rA) * 512 + (k0) + gAr * 8]; \
    ka7_ = *(const float4*)&w_kv[(size_t)(192 + rA) * 512 + (k0) + gAr * 8 + 4]; }
#define KC_LOADB(k0) { \
    kb0_ = *(const float4*)&Bb[(size_t)((k0) + rB) * 1024 + gB * 4]; }
#define KC_WRITEA() { uint4 p; \
    p.x = pack2(ka0_.x, ka0_.y); p.y = pack2(ka0_.z, ka0_.w); \
    p.z = pack2(ka1_.x, ka1_.y); p.w = pack2(ka1_.z, ka1_.w); \
    *(uint4*)((char*)lA + (size_t)((rA)       * 8 + gw) * 16) = p; \
    p.x = pack2(ka2_.x, ka2_.y); p.y = pack2(ka2_.z, ka2_.w); \
    p.z = pack2(ka3_.x, ka3_.y); p.w = pack2(ka3_.z, ka3_.w); \
    *(uint4*)((char*)lA + (size_t)((64 + rA)  * 8 + gw) * 16) = p; \
    p.x = pack2(ka4_.x, ka4_.y); p.y = pack2(ka4_.z, ka4_.w); \
    p.z = pack2(ka5_.x, ka5_.y); p.w = pack2(ka5_.z, ka5_.w); \
    *(uint4*)((char*)lA + (size_t)((128 + rA) * 8 + gw) * 16) = p; \
    p.x = pack2(ka6_.x, ka6_.y); p.y = pack2(ka6_.z, ka6_.w); \
    p.z = pack2(ka7_.x, ka7_.y); p.w = pack2(ka7_.z, ka7_.w); \
    *(uint4*)((char*)lA + (size_t)((192 + rA) * 8 + gw) * 16) = p; }
#define KC_WRITEB() { \
    *(float4*)((char*)scratch + (rB) * 128 + ((gB ^ ((rB >> 1) & 7)) * 16)) = kb0_; }
#define KC_PACKB() if (t < 256) { \
    int js = sj4 ^ (sp & 7); \
    float4 s0 = *(const float4*)((char*)scratch + (2*sp)   * 128 + js * 16); \
    float4 s2 = *(const float4*)((char*)scratch + (2*sp+1) * 128 + js * 16); \
    float c0v[4] = {s0.x, s0.y, s0.z, s0.w}; \
    float c1v[4] = {s2.x, s2.y, s2.z, s2.w}; \
    _Pragma("unroll") \
    for (int w4 = 0; w4 < 4; ++w4) { \
        int n = sj4 * 4 + w4; \
        unsigned pk = pack2(c0v[w4], c1v[w4]); \
        *(unsigned*)((char*)lB + n * 128 + (((sp >> 2) ^ (n & 7)) * 16) + (sp & 3) * 4) = pk; \
    } }
    KC_LOADA(0); KC_LOADB(0);
    f32x4 acc[2][2] = {};
    for (int it = 0; it < 8; ++it) {
        KC_WRITEA();
        KC_WRITEB();
        __syncthreads();
        if (it < 7) { KC_LOADA(it * 64 + 64); KC_LOADB(it * 64 + 64); }  // prefetch
        // x-stats loads: independent latency filler
        xv0_ = xc[t + 512 * (2 * it)];
        xv1_ = xc[t + 512 * (2 * it + 1)];
        KC_PACKB();
        __syncthreads();
        #pragma unroll
        for (int ks = 0; ks < 2; ++ks) {
            bf16x8 av[2], bv[2];
            #pragma unroll
            for (int mi = 0; mi < 2; ++mi) {
                int ar = w * 32 + mi * 16 + lr;
                int q = (ks * 4 + lg) ^ (ar & 7);
                av[mi] = *(const bf16x8*)((const char*)lA + ar * 128 + q * 16);
            }
            #pragma unroll
            for (int ni = 0; ni < 2; ++ni) {
                int br = ni * 16 + lr;
                int q = (ks * 4 + lg) ^ (br & 7);
                bv[ni] = *(const bf16x8*)((const char*)lB + br * 128 + q * 16);
            }
            #pragma unroll
            for (int mi = 0; mi < 2; ++mi)
                #pragma unroll
                for (int ni = 0; ni < 2; ++ni)
                    acc[mi][ni] = __builtin_amdgcn_mfma_f32_16x16x32_bf16(
                        av[mi], bv[ni], acc[mi][ni], 0, 0, 0);
        }
        __syncthreads();
        float xs = (xv0_.x + xv0_.y + xv0_.z + xv0_.w)
                 + (xv1_.x + xv1_.y + xv1_.z + xv1_.w);
        float xss = xv0_.x*xv0_.x + xv0_.y*xv0_.y + xv0_.z*xv0_.z + xv0_.w*xv0_.w
                  + xv1_.x*xv1_.x + xv1_.y*xv1_.y + xv1_.z*xv1_.z + xv1_.w*xv1_.w;
        sA += xs; ssA += xss;
    }
#undef KC_LOADA
#undef KC_LOADB
#undef KC_WRITEA
#undef KC_WRITEB
#undef KC_PACKB
    // --- epilogue: bias, exp(k), rowsum partials, bf16 [256][32] tile to lA ---
    bool isK = (w < 4);
    float bk[2][4];
    #pragma unroll
    for (int mi = 0; mi < 2; ++mi)
        #pragma unroll
        for (int reg = 0; reg < 4; ++reg)
            bk[mi][reg] = b_kv[w * 32 + mi * 16 + lg * 4 + reg];
    float rs[2][4];
    #pragma unroll
    for (int mi = 0; mi < 2; ++mi)
        #pragma unroll
        for (int reg = 0; reg < 4; ++reg) rs[mi][reg] = 0.f;
    #pragma unroll
    for (int mi = 0; mi < 2; ++mi) {
        #pragma unroll
        for (int ni = 0; ni < 2; ++ni) {
            #pragma unroll
            for (int reg = 0; reg < 4; ++reg) {
                int R = w * 32 + mi * 16 + lg * 4 + reg;
                int N = ni * 16 + lr;
                float val = acc[mi][ni][reg] + bk[mi][reg];
                ushort uo;
                if (isK) {
                    uo = f2bf(__expf(val));
                    rs[mi][reg] += bflo((unsigned)uo);
                } else {
                    uo = f2bf(val);
                }
                *(ushort*)((char*)lA + R * 64 + (((N >> 3) ^ (R & 3)) * 16) + (N & 7) * 2) = uo;
            }
        }
    }
    if (isK) {
        #pragma unroll
        for (int mi = 0; mi < 2; ++mi) {
            #pragma unroll
            for (int reg = 0; reg < 4; ++reg) {
                float v = rs[mi][reg];
                v += __shfl_xor(v, 1, 64);
                v += __shfl_xor(v, 2, 64);
                v += __shfl_xor(v, 4, 64);
                v += __shfl_xor(v, 8, 64);
                if (lr == 0)
                    rsp[(size_t)(b * 32 + nc) * 128 + w * 32 + mi * 16 + lg * 4 + reg] = v;
            }
        }
    }
    __syncthreads();
    // --- PV: head h=w (waves 0-3): ctx[h][d][e] = sum_{n<32} expk*v, 1 MFMA/quadrant
    if (isK) {
        int ar0 = w * 32 + lr,            qa0 = lg ^ (ar0 & 3);
        int ar1 = w * 32 + 16 + lr,       qa1 = lg ^ (ar1 & 3);
        int br0 = 128 + w * 32 + lr,      qb0 = lg ^ (br0 & 3);
        int br1 = 128 + w * 32 + 16 + lr, qb1 = lg ^ (br1 & 3);
        bf16x8 pa0 = *(const bf16x8*)((const char*)lA + ar0 * 64 + qa0 * 16);
        bf16x8 pa1 = *(const bf16x8*)((const char*)lA + ar1 * 64 + qa1 * 16);
        bf16x8 pv0 = *(const bf16x8*)((const char*)lA + br0 * 64 + qb0 * 16);
        bf16x8 pv1 = *(const bf16x8*)((const char*)lA + br1 * 64 + qb1 * 16);
        f32x4 c00 = {}, c01 = {}, c10 = {}, c11 = {};
        c00 = __builtin_amdgcn_mfma_f32_16x16x32_bf16(pa0, pv0, c00, 0, 0, 0);
        c01 = __builtin_amdgcn_mfma_f32_16x16x32_bf16(pa0, pv1, c01, 0, 0, 0);
        c10 = __builtin_amdgcn_mfma_f32_16x16x32_bf16(pa1, pv0, c10, 0, 0, 0);
        c11 = __builtin_amdgcn_mfma_f32_16x16x32_bf16(pa1, pv1, c11, 0, 0, 0);
        float* cp = ctxp + (size_t)(b * 32 + nc) * 4096 + w * 1024;
        #pragma unroll
        for (int reg = 0; reg < 4; ++reg) {
            int d0 = lg * 4 + reg;
            cp[d0 * 32 + lr]              = c00[reg];
            cp[d0 * 32 + 16 + lr]         = c01[reg];
            cp[(16 + d0) * 32 + lr]       = c10[reg];
            cp[(16 + d0) * 32 + 16 + lr]  = c11[reg];
        }
    }
    // --- GN stats reduction (all 8 waves, one group) ---
    #pragma unroll
    for (int off = 32; off > 0; off >>= 1) {
        sA  += __shfl_down(sA, off, 64);
        ssA += __shfl_down(ssA, off, 64);
    }
    if ((t & 63) == 0) { red2[w][0] = sA; red2[w][1] = ssA; }
    __syncthreads();
    if (t == 0) {
        float S = 0.f, SS = 0.f;
        #pragma unroll
        for (int i = 0; i < 8; ++i) { S += red2[i][0]; SS += red2[i][1]; }
        int bg = b * 32 + nc;
        statacc[bg * 2]     = S;
        statacc[bg * 2 + 1] = SS;
    }
}

// ---------------------------------------------------------------------------
// L2: A-fold: sum 32 ctx/rowsum partials, normalize, M = w_out@ctx^T in LDS,
// A16[b,o,c] = bf16(wt*s), biasb[b,o] = sum_c wt*t + M.b_q + b_out
__global__ __launch_bounds__(256) void a_kernel(const float* __restrict__ ctxp,
                                                const float* __restrict__ rsp,
                                                const float* __restrict__ w_out,
                                                const float* __restrict__ w_q,
                                                const float* __restrict__ b_q,
                                                const float* __restrict__ statacc,
                                                const float* __restrict__ gn_w,
                                                const float* __restrict__ gn_b,
                                                const float* __restrict__ b_out,
                                                ushort* __restrict__ A16,
                                                float* __restrict__ biasb) {
    __shared__ float ctxl[4][32][33];
    __shared__ float wol[16][128];
    __shared__ float ml[16][128];
    __shared__ float cbuf[256][17];
    __shared__ float pbuf[16][17];
    __shared__ float rsinv[128];
    int b = blockIdx.x >> 4, ot = (blockIdx.x & 15) << 4;
    int t = threadIdx.x;
    if (t < 128) {
        float s = 0.f;
        #pragma unroll
        for (int nc = 0; nc < 32; ++nc)
            s += rsp[(size_t)(b * 32 + nc) * 128 + t];
        rsinv[t] = 1.f / s;
    }
    #pragma unroll
    for (int j = 0; j < 8; ++j) {
        int e = t + 256 * j;            // 0..2047
        wol[e >> 7][e & 127] = w_out[(ot + (e >> 7)) * 128 + (e & 127)];
    }
    __syncthreads();
    #pragma unroll
    for (int j = 0; j < 16; ++j) {
        int e = t + 256 * j;            // 0..4095
        float v = 0.f;
        #pragma unroll
        for (int nc = 0; nc < 32; ++nc)
            v += ctxp[(size_t)(b * 32 + nc) * 4096 + e];
        ctxl[e >> 10][(e >> 5) & 31][e & 31] = v * rsinv[e >> 5];
    }
    __syncthreads();
    #pragma unroll
    for (int j = 0; j < 8; ++j) {
        int e = t + 256 * j;
        int o = e >> 7, hd = e & 127, h = hd >> 5, d = hd & 31;
        float acc = 0.f;
        #pragma unroll
        for (int ee = 0; ee < 32; ++ee) acc += wol[o][h * 32 + ee] * ctxl[h][d][ee];
        ml[o][hd] = acc;
    }
    __syncthreads();
    int c = t, g = c >> 3;
    float a0 = statacc[(b * 32 + g) * 2], a1 = statacc[(b * 32 + g) * 2 + 1];
    float mu  = a0 * (1.f / 32768.f);
    float var = a1 * (1.f / 32768.f) - mu * mu;
    float sc = rsqrtf(var + 1e-5f) * gn_w[c];
    float tc = gn_b[c] - mu * sc;
    float wt[16];
    #pragma unroll
    for (int o = 0; o < 16; ++o) wt[o] = 0.f;
    for (int hd = 0; hd < 128; ++hd) {
        float wq = w_q[hd * 256 + c];
        #pragma unroll
        for (int o = 0; o < 16; ++o) wt[o] += ml[o][hd] * wq;
    }
    ushort* Abp = A16 + ((size_t)b * 256 + ot) * 256 + c;
    #pragma unroll
    for (int o = 0; o < 16; ++o) {
        Abp[(size_t)o * 256] = f2bf(wt[o] * sc);
        cbuf[c][o] = wt[o] * tc;
    }
    __syncthreads();
    {
        int o = t >> 4, seg = t & 15;
        float p = 0.f;
        #pragma unroll
        for (int i = 0; i < 16; ++i) p += cbuf[seg * 16 + i][o];
        pbuf[o][seg] = p;
    }
    __syncthreads();
    if (t < 16) {
        int o = t;
        float sum = 0.f;
        #pragma unroll
        for (int s2 = 0; s2 < 16; ++s2) sum += pbuf[o][s2];
        float md = 0.f;
        #pragma unroll 8
        for (int hd = 0; hd < 128; ++hd) md += ml[o][hd] * b_q[hd];
        biasb[(size_t)b * 256 + ot + o] = sum + md + b_out[ot + o];
    }
}

// ---------------------------------------------------------------------------
// L3: out = A16 @ x^T + bias.  BM=256, BN=128, BK=64; 8 waves (4x2), 512 thr.
// A and B reg-staged via NAMED regs with next-tile prefetch.
__global__ __launch_bounds__(512) void out_gemm_fused(const ushort* __restrict__ A16,
                                                      const float* __restrict__ x,
                                                      const float* __restrict__ biasb,
                                                      float* __restrict__ out) {
    __shared__ ushort lA[256 * 64];     // 32 KB
    __shared__ ushort lB[128 * 64];     // 16 KB
    __shared__ float scratch[64 * 128]; // 32 KB, granule-swizzled
    int b = blockIdx.y;
    int n0 = blockIdx.x * 128;
    int t = threadIdx.x;
    int l = t & 63, wid = t >> 6;
    int wr = wid >> 1, wc = wid & 1;          // 4 x 2 wave grid
    int lr = l & 15, lg = l >> 4;
    const ushort* Ab = A16 + (size_t)b * 65536;
    const float* xb = x + (size_t)b * 256 * 4096 + n0;
    int sp = t & 31, sj = t >> 5;             // c-pair (2sp,2sp+1), n-octet (16)
    uint4 a0_, a1_, a2_, a3_;
    float4 b0_, b1_, b2_, b3_;
    int rA = t >> 3, gA = (t & 7) ^ (rA & 7); // (64k+rA)&7 == rA&7
    int rB = t >> 5, gB = t & 31;
#define OG_LOADA(k0) { \
    a0_ = *(const uint4*)(Ab + (size_t)(rA)       * 256 + (k0) + gA * 8); \
    a1_ = *(const uint4*)(Ab + (size_t)(64 + rA)  * 256 + (k0) + gA * 8); \
    a2_ = *(const uint4*)(Ab + (size_t)(128 + rA) * 256 + (k0) + gA * 8); \
    a3_ = *(const uint4*)(Ab + (size_t)(192 + rA) * 256 + (k0) + gA * 8); }
#define OG_LOADB(k0) { \
    b0_ = *(const float4*)&xb[(size_t)((k0) + rB)      * 4096 + gB * 4]; \
    b1_ = *(const float4*)&xb[(size_t)((k0) + 16 + rB) * 4096 + gB * 4]; \
    b2_ = *(const float4*)&xb[(size_t)((k0) + 32 + rB) * 4096 + gB * 4]; \
    b3_ = *(const float4*)&xb[(size_t)((k0) + 48 + rB) * 4096 + gB * 4]; }
    OG_LOADA(0); OG_LOADB(0);
    f32x4 acc[4][4] = {};
    for (int it = 0; it < 4; ++it) {
        *(uint4*)((char*)lA + (size_t)t * 16)          = a0_;
        *(uint4*)((char*)lA + (size_t)(512 + t) * 16)  = a1_;
        *(uint4*)((char*)lA + (size_t)(1024 + t) * 16) = a2_;
        *(uint4*)((char*)lA + (size_t)(1536 + t) * 16) = a3_;
        *(float4*)((char*)scratch + (rB)      * 512 + (gB ^ (((rB)      >> 1) & 31)) * 16) = b0_;
        *(float4*)((char*)scratch + (16 + rB) * 512 + (gB ^ (((16 + rB) >> 1) & 31)) * 16) = b1_;
        *(float4*)((char*)scratch + (32 + rB) * 512 + (gB ^ (((32 + rB) >> 1) & 31)) * 16) = b2_;
        *(float4*)((char*)scratch + (48 + rB) * 512 + (gB ^ (((48 + rB) >> 1) & 31)) * 16) = b3_;
        __syncthreads();
        if (it < 3) { OG_LOADA(it * 64 + 64); OG_LOADB(it * 64 + 64); }   // prefetch
        {
            int swz = sp & 31;
            float4 s0 = *(const float4*)((char*)scratch + (2*sp)   * 512 + ((2*sj)   ^ swz) * 16);
            float4 s1 = *(const float4*)((char*)scratch + (2*sp)   * 512 + ((2*sj+1) ^ swz) * 16);
            float4 s2 = *(const float4*)((char*)scratch + (2*sp+1) * 512 + ((2*sj)   ^ swz) * 16);
            float4 s3 = *(const float4*)((char*)scratch + (2*sp+1) * 512 + ((2*sj+1) ^ swz) * 16);
            float c0v[8] = {s0.x, s0.y, s0.z, s0.w, s1.x, s1.y, s1.z, s1.w};
            float c1v[8] = {s2.x, s2.y, s2.z, s2.w, s3.x, s3.y, s3.z, s3.w};
            #pragma unroll
            for (int w = 0; w < 8; ++w) {
                int n = sj * 8 + w;
                unsigned pk = pack2(c0v[w], c1v[w]);
                *(unsigned*)((char*)lB + n * 128 + (((sp >> 2) ^ (n & 7)) * 16) + (sp & 3) * 4) = pk;
            }
        }
        __syncthreads();
        #pragma unroll
        for (int ks = 0; ks < 2; ++ks) {
            bf16x8 av[4], bv[4];
            #pragma unroll
            for (int mi = 0; mi < 4; ++mi) {
                int ar = wr * 64 + mi * 16 + lr;
                int q = (ks * 4 + lg) ^ (ar & 7);
                av[mi] = *(const bf16x8*)((const char*)lA + ar * 128 + q * 16);
            }
            #pragma unroll
            for (int ni = 0; ni < 4; ++ni) {
                int br = wc * 64 + ni * 16 + lr;
                int q = (ks * 4 + lg) ^ (br & 7);
                bv[ni] = *(const bf16x8*)((const char*)lB + br * 128 + q * 16);
            }
            #pragma unroll
            for (int mi = 0; mi < 4; ++mi)
                #pragma unroll
                for (int ni = 0; ni < 4; ++ni)
                    acc[mi][ni] = __builtin_amdgcn_mfma_f32_16x16x32_bf16(
                        av[mi], bv[ni], acc[mi][ni], 0, 0, 0);
        }
        __syncthreads();
    }
#undef OG_LOADA
#undef OG_LOADB
    const float* bp = biasb + (size_t)b * 256;
    int orow = wr * 64, ocol = n0 + wc * 64 + lr;
    #pragma unroll
    for (int mi = 0; mi < 4; ++mi) {
        int rb = orow + mi * 16 + lg * 4;
        float4 b4 = *(const float4*)&bp[rb];
        float bvr[4] = {b4.x, b4.y, b4.z, b4.w};
        #pragma unroll
        for (int ni = 0; ni < 4; ++ni) {
            int cc = ocol + ni * 16;
            #pragma unroll
            for (int r = 0; r < 4; ++r)
                out[((size_t)b * 256 + rb + r) * 4096 + cc] = acc[mi][ni][r] + bvr[r];
        }
    }
}

extern "C" void kernel_launch(void* const* d_in, const int* in_sizes, int n_in,
                              void* d_out, int out_size, void* d_ws, size_t ws_size,
                              hipStream_t stream) {
    const float* x     = (const float*)d_in[0];
    const float* cond  = (const float*)d_in[1];
    const float* gn_w  = (const float*)d_in[2];
    const float* gn_b  = (const float*)d_in[3];
    const float* w_q   = (const float*)d_in[4];
    const float* b_q   = (const float*)d_in[5];
    const float* w_kv  = (const float*)d_in[6];
    const float* b_kv  = (const float*)d_in[7];
    const float* w_out = (const float*)d_in[8];
    const float* b_out = (const float*)d_in[9];
    float* out = (float*)d_out;

    float* f       = (float*)d_ws;
    float* statacc = f;                     // 1024 floats (plain stores)
    float* rsp     = f + 1024;              // 16*32*128 = 65536 floats
    float* ctxp    = f + 66560;             // 16*32*4096 = 2097152 floats
    float* biasb   = f + 2163712;           // 4096 floats
    ushort* A16    = (ushort*)(f + 2167808);// 1048576 ushorts

    // L1: kv GEMM (BN=32, 512 blocks = 2/CU) + fused exp/PV + GN stats weave
    kvctx_kernel<<<512, 512, 0, stream>>>(w_kv, cond, b_kv, x, statacc, rsp, ctxp);
    // L2: fold everything into per-batch A (bf16) + bias
    a_kernel<<<256, 256, 0, stream>>>(ctxp, rsp, w_out, w_q, b_q, statacc,
                                      gn_w, gn_b, b_out, A16, biasb);
    // L3: out = A @ x^T + bias
    out_gemm_fused<<<dim3(32, 16), 512, 0, stream>>>(A16, x, biasb, out);
}

// Round 17
// 78.536 us; speedup vs baseline: 2.3438x; 2.3438x over previous
//
#include <hip/hip_runtime.h>
#include <hip/hip_bf16.h>

typedef __attribute__((ext_vector_type(8))) short bf16x8;
typedef __attribute__((ext_vector_type(4))) float f32x4;

__device__ __forceinline__ ushort f2bf(float f) {
    __hip_bfloat16 h = __float2bfloat16(f);
    return __builtin_bit_cast(ushort, h);
}
__device__ __forceinline__ unsigned pack2(float a, float b) {
    return (unsigned)f2bf(a) | ((unsigned)f2bf(b) << 16);
}
__device__ __forceinline__ float bflo(unsigned u) { return __uint_as_float(u << 16); }

// ---------------------------------------------------------------------------
// L1 kvctx: 512 blocks (2/CU), one per (b, n-chunk of 32):
//   kv = w_kv @ cond chunk (BM=256, BN=32, BK=64, K=512, 8 waves) with fused
//   epilogue: bias + exp(k-half) + rowsum partials -> rsp, bf16 tile in LDS,
//   per-head PV contraction (single K=32 MFMA per quadrant) -> ctxp.
//   PLUS GN stats: block (b,nc) owns group (b,nc) x-slice, woven into K-loop.
__global__ __launch_bounds__(512) void kvctx_kernel(const float* __restrict__ w_kv,
                                                    const float* __restrict__ cond,
                                                    const float* __restrict__ b_kv,
                                                    const float* __restrict__ x,
                                                    float* __restrict__ statacc,
                                                    float* __restrict__ rsp,
                                                    float* __restrict__ ctxp) {
    __shared__ ushort lA[256 * 64];     // 32 KB (reused as [256][32] bf16 kv tile)
    __shared__ ushort lB[32 * 64];      // 4 KB
    __shared__ float scratch[64 * 32];  // 8 KB, granule-swizzled
    __shared__ float red2[8][2];
    int bid = blockIdx.x, t = threadIdx.x;
    int b = bid >> 5, nc = bid & 31;
    int col0 = nc * 32;
    int l = t & 63, w = t >> 6;          // wave 0..7, rows w*32..w*32+31
    int lr = l & 15, lg = l >> 4;
    const float* Bb = cond + (size_t)b * 512 * 1024 + col0;
    const float4* xc = (const float4*)(x + (size_t)b * 1048576 + (size_t)nc * 32768);
    int rA = t >> 3, gAr = t & 7, gw = gAr ^ (rA & 7);  // (64m+rA)&7==rA&7
    int rB = t >> 3, gB = t & 7;         // B: row 0..63, granule 0..7 (32 floats/row)
    int sp = t & 31, sj4 = (t >> 5) & 7; // PACKB (t<256): k-pair, n-quad
    float4 ka0_, ka1_, ka2_, ka3_, ka4_, ka5_, ka6_, ka7_;
    float4 kb0_;
    float4 xv0_, xv1_;
    float sA = 0.f, ssA = 0.f;
#define KC_LOADA(k0) { \
    ka0_ = *(const float4*)&w_kv[(size_t)(rA)       * 512 + (k0) + gAr * 8]; \
    ka1_ = *(const float4*)&w_kv[(size_t)(rA)       * 512 + (k0) + gAr * 8 + 4]; \
    ka2_ = *(const float4*)&w_kv[(size_t)(64 + rA)  * 512 + (k0) + gAr * 8]; \
    ka3_ = *(const float4*)&w_kv[(size_t)(64 + rA)  * 512 + (k0) + gAr * 8 + 4]; \
    ka4_ = *(const float4*)&w_kv[(size_t)(128 + rA) * 512 + (k0) + gAr * 8]; \
    ka5_ = *(const float4*)&w_kv[(size_t)(128 + rA) * 512 + (k0) + gAr * 8 + 4]; \
    ka6_ = *(const float4*)&w_kv[(size_t)(192 + rA) * 512 + (k0) + gAr * 8]; \
    ka7_ = *(const float4*)&w_kv[(size_t)(192 + rA) * 512 + (k0) + gAr * 8 + 4]; }
#define KC_LOADB(k0) { \
    kb0_ = *(const float4*)&Bb[(size_t)((k0) + rB) * 1024 + gB * 4]; }
#define KC_WRITEA() { uint4 p; \
    p.x = pack2(ka0_.x, ka0_.y); p.y = pack2(ka0_.z, ka0_.w); \
    p.z = pack2(ka1_.x, ka1_.y); p.w = pack2(ka1_.z, ka1_.w); \
    *(uint4*)((char*)lA + (size_t)((rA)       * 8 + gw) * 16) = p; \
    p.x = pack2(ka2_.x, ka2_.y); p.y = pack2(ka2_.z, ka2_.w); \
    p.z = pack2(ka3_.x, ka3_.y); p.w = pack2(ka3_.z, ka3_.w); \
    *(uint4*)((char*)lA + (size_t)((64 + rA)  * 8 + gw) * 16) = p; \
    p.x = pack2(ka4_.x, ka4_.y); p.y = pack2(ka4_.z, ka4_.w); \
    p.z = pack2(ka5_.x, ka5_.y); p.w = pack2(ka5_.z, ka5_.w); \
    *(uint4*)((char*)lA + (size_t)((128 + rA) * 8 + gw) * 16) = p; \
    p.x = pack2(ka6_.x, ka6_.y); p.y = pack2(ka6_.z, ka6_.w); \
    p.z = pack2(ka7_.x, ka7_.y); p.w = pack2(ka7_.z, ka7_.w); \
    *(uint4*)((char*)lA + (size_t)((192 + rA) * 8 + gw) * 16) = p; }
#define KC_WRITEB() { \
    *(float4*)((char*)scratch + (rB) * 128 + ((gB ^ ((rB >> 1) & 7)) * 16)) = kb0_; }
#define KC_PACKB() if (t < 256) { \
    int js = sj4 ^ (sp & 7); \
    float4 s0 = *(const float4*)((char*)scratch + (2*sp)   * 128 + js * 16); \
    float4 s2 = *(const float4*)((char*)scratch + (2*sp+1) * 128 + js * 16); \
    float c0v[4] = {s0.x, s0.y, s0.z, s0.w}; \
    float c1v[4] = {s2.x, s2.y, s2.z, s2.w}; \
    _Pragma("unroll") \
    for (int w4 = 0; w4 < 4; ++w4) { \
        int n = sj4 * 4 + w4; \
        unsigned pk = pack2(c0v[w4], c1v[w4]); \
        *(unsigned*)((char*)lB + n * 128 + (((sp >> 2) ^ (n & 7)) * 16) + (sp & 3) * 4) = pk; \
    } }
    KC_LOADA(0); KC_LOADB(0);
    f32x4 acc[2][2] = {};
    for (int it = 0; it < 8; ++it) {
        KC_WRITEA();
        KC_WRITEB();
        __syncthreads();
        if (it < 7) { KC_LOADA(it * 64 + 64); KC_LOADB(it * 64 + 64); }  // prefetch
        // x-stats loads: independent latency filler
        xv0_ = xc[t + 512 * (2 * it)];
        xv1_ = xc[t + 512 * (2 * it + 1)];
        KC_PACKB();
        __syncthreads();
        #pragma unroll
        for (int ks = 0; ks < 2; ++ks) {
            bf16x8 av[2], bv[2];
            #pragma unroll
            for (int mi = 0; mi < 2; ++mi) {
                int ar = w * 32 + mi * 16 + lr;
                int q = (ks * 4 + lg) ^ (ar & 7);
                av[mi] = *(const bf16x8*)((const char*)lA + ar * 128 + q * 16);
            }
            #pragma unroll
            for (int ni = 0; ni < 2; ++ni) {
                int br = ni * 16 + lr;
                int q = (ks * 4 + lg) ^ (br & 7);
                bv[ni] = *(const bf16x8*)((const char*)lB + br * 128 + q * 16);
            }
            #pragma unroll
            for (int mi = 0; mi < 2; ++mi)
                #pragma unroll
                for (int ni = 0; ni < 2; ++ni)
                    acc[mi][ni] = __builtin_amdgcn_mfma_f32_16x16x32_bf16(
                        av[mi], bv[ni], acc[mi][ni], 0, 0, 0);
        }
        __syncthreads();
        float xs = (xv0_.x + xv0_.y + xv0_.z + xv0_.w)
                 + (xv1_.x + xv1_.y + xv1_.z + xv1_.w);
        float xss = xv0_.x*xv0_.x + xv0_.y*xv0_.y + xv0_.z*xv0_.z + xv0_.w*xv0_.w
                  + xv1_.x*xv1_.x + xv1_.y*xv1_.y + xv1_.z*xv1_.z + xv1_.w*xv1_.w;
        sA += xs; ssA += xss;
    }
#undef KC_LOADA
#undef KC_LOADB
#undef KC_WRITEA
#undef KC_WRITEB
#undef KC_PACKB
    // --- epilogue: bias, exp(k), rowsum partials, bf16 [256][32] tile to lA ---
    bool isK = (w < 4);
    float bk[2][4];
    #pragma unroll
    for (int mi = 0; mi < 2; ++mi)
        #pragma unroll
        for (int reg = 0; reg < 4; ++reg)
            bk[mi][reg] = b_kv[w * 32 + mi * 16 + lg * 4 + reg];
    float rs[2][4];
    #pragma unroll
    for (int mi = 0; mi < 2; ++mi)
        #pragma unroll
        for (int reg = 0; reg < 4; ++reg) rs[mi][reg] = 0.f;
    #pragma unroll
    for (int mi = 0; mi < 2; ++mi) {
        #pragma unroll
        for (int ni = 0; ni < 2; ++ni) {
            #pragma unroll
            for (int reg = 0; reg < 4; ++reg) {
                int R = w * 32 + mi * 16 + lg * 4 + reg;
                int N = ni * 16 + lr;
                float val = acc[mi][ni][reg] + bk[mi][reg];
                ushort uo;
                if (isK) {
                    uo = f2bf(__expf(val));
                    rs[mi][reg] += bflo((unsigned)uo);
                } else {
                    uo = f2bf(val);
                }
                *(ushort*)((char*)lA + R * 64 + (((N >> 3) ^ (R & 3)) * 16) + (N & 7) * 2) = uo;
            }
        }
    }
    if (isK) {
        #pragma unroll
        for (int mi = 0; mi < 2; ++mi) {
            #pragma unroll
            for (int reg = 0; reg < 4; ++reg) {
                float v = rs[mi][reg];
                v += __shfl_xor(v, 1, 64);
                v += __shfl_xor(v, 2, 64);
                v += __shfl_xor(v, 4, 64);
                v += __shfl_xor(v, 8, 64);
                if (lr == 0)
                    rsp[(size_t)(b * 32 + nc) * 128 + w * 32 + mi * 16 + lg * 4 + reg] = v;
            }
        }
    }
    __syncthreads();
    // --- PV: head h=w (waves 0-3): ctx[h][d][e] = sum_{n<32} expk*v, 1 MFMA/quadrant
    if (isK) {
        int ar0 = w * 32 + lr,            qa0 = lg ^ (ar0 & 3);
        int ar1 = w * 32 + 16 + lr,       qa1 = lg ^ (ar1 & 3);
        int br0 = 128 + w * 32 + lr,      qb0 = lg ^ (br0 & 3);
        int br1 = 128 + w * 32 + 16 + lr, qb1 = lg ^ (br1 & 3);
        bf16x8 pa0 = *(const bf16x8*)((const char*)lA + ar0 * 64 + qa0 * 16);
        bf16x8 pa1 = *(const bf16x8*)((const char*)lA + ar1 * 64 + qa1 * 16);
        bf16x8 pv0 = *(const bf16x8*)((const char*)lA + br0 * 64 + qb0 * 16);
        bf16x8 pv1 = *(const bf16x8*)((const char*)lA + br1 * 64 + qb1 * 16);
        f32x4 c00 = {}, c01 = {}, c10 = {}, c11 = {};
        c00 = __builtin_amdgcn_mfma_f32_16x16x32_bf16(pa0, pv0, c00, 0, 0, 0);
        c01 = __builtin_amdgcn_mfma_f32_16x16x32_bf16(pa0, pv1, c01, 0, 0, 0);
        c10 = __builtin_amdgcn_mfma_f32_16x16x32_bf16(pa1, pv0, c10, 0, 0, 0);
        c11 = __builtin_amdgcn_mfma_f32_16x16x32_bf16(pa1, pv1, c11, 0, 0, 0);
        float* cp = ctxp + (size_t)(b * 32 + nc) * 4096 + w * 1024;
        #pragma unroll
        for (int reg = 0; reg < 4; ++reg) {
            int d0 = lg * 4 + reg;
            cp[d0 * 32 + lr]              = c00[reg];
            cp[d0 * 32 + 16 + lr]         = c01[reg];
            cp[(16 + d0) * 32 + lr]       = c10[reg];
            cp[(16 + d0) * 32 + 16 + lr]  = c11[reg];
        }
    }
    // --- GN stats reduction (all 8 waves, one group) ---
    #pragma unroll
    for (int off = 32; off > 0; off >>= 1) {
        sA  += __shfl_down(sA, off, 64);
        ssA += __shfl_down(ssA, off, 64);
    }
    if ((t & 63) == 0) { red2[w][0] = sA; red2[w][1] = ssA; }
    __syncthreads();
    if (t == 0) {
        float S = 0.f, SS = 0.f;
        #pragma unroll
        for (int i = 0; i < 8; ++i) { S += red2[i][0]; SS += red2[i][1]; }
        int bg = b * 32 + nc;
        statacc[bg * 2]     = S;
        statacc[bg * 2 + 1] = SS;
    }
}

// ---------------------------------------------------------------------------
// L2 reduce: 256 blocks, one per (b, 256-elem segment of ctx):
//   rowsum reduce (1 load/thread + shfl tree over 32 nc) -> rsinv,
//   ctx partial sum (32 coalesced loads/thread), normalize -> ctxn[b][4096].
__global__ __launch_bounds__(256) void reduce_kernel(const float* __restrict__ ctxp,
                                                     const float* __restrict__ rsp,
                                                     float* __restrict__ ctxn) {
    __shared__ float rsinv[8];
    int b = blockIdx.x >> 4, seg = blockIdx.x & 15;
    int t = threadIdx.x;
    {
        int row = seg * 8 + (t >> 5), nc = t & 31;
        float p = rsp[(size_t)(b * 32 + nc) * 128 + row];
        #pragma unroll
        for (int off = 1; off < 32; off <<= 1) p += __shfl_xor(p, off, 32);
        if ((t & 31) == 0) rsinv[t >> 5] = 1.f / p;
    }
    __syncthreads();
    int e = seg * 256 + t;
    float v = 0.f;
    #pragma unroll
    for (int nc = 0; nc < 32; ++nc)
        v += ctxp[(size_t)(b * 32 + nc) * 4096 + e];
    ctxn[(size_t)b * 4096 + e] = v * rsinv[t >> 5];
}

// ---------------------------------------------------------------------------
// L3: A-fold: M = w_out@ctx^T in LDS (ctx pre-normalized), then
// A16[b,o,c] = bf16(wt*s), biasb[b,o] = sum_c wt*t + M.b_q + b_out
__global__ __launch_bounds__(256) void a_kernel(const float* __restrict__ ctxn,
                                                const float* __restrict__ w_out,
                                                const float* __restrict__ w_q,
                                                const float* __restrict__ b_q,
                                                const float* __restrict__ statacc,
                                                const float* __restrict__ gn_w,
                                                const float* __restrict__ gn_b,
                                                const float* __restrict__ b_out,
                                                ushort* __restrict__ A16,
                                                float* __restrict__ biasb) {
    __shared__ float ctxl[4][32][33];
    __shared__ float wol[16][128];
    __shared__ float ml[16][128];
    __shared__ float cbuf[256][17];
    __shared__ float pbuf[16][17];
    int b = blockIdx.x >> 4, ot = (blockIdx.x & 15) << 4;
    int t = threadIdx.x;
    #pragma unroll
    for (int j = 0; j < 16; ++j) {
        int e = t + 256 * j;            // 0..4095
        ctxl[e >> 10][(e >> 5) & 31][e & 31] = ctxn[(size_t)b * 4096 + e];
    }
    #pragma unroll
    for (int j = 0; j < 8; ++j) {
        int e = t + 256 * j;            // 0..2047
        wol[e >> 7][e & 127] = w_out[(ot + (e >> 7)) * 128 + (e & 127)];
    }
    __syncthreads();
    #pragma unroll
    for (int j = 0; j < 8; ++j) {
        int e = t + 256 * j;
        int o = e >> 7, hd = e & 127, h = hd >> 5, d = hd & 31;
        float acc = 0.f;
        #pragma unroll
        for (int ee = 0; ee < 32; ++ee) acc += wol[o][h * 32 + ee] * ctxl[h][d][ee];
        ml[o][hd] = acc;
    }
    __syncthreads();
    int c = t, g = c >> 3;
    float a0 = statacc[(b * 32 + g) * 2], a1 = statacc[(b * 32 + g) * 2 + 1];
    float mu  = a0 * (1.f / 32768.f);
    float var = a1 * (1.f / 32768.f) - mu * mu;
    float sc = rsqrtf(var + 1e-5f) * gn_w[c];
    float tc = gn_b[c] - mu * sc;
    float wt[16];
    #pragma unroll
    for (int o = 0; o < 16; ++o) wt[o] = 0.f;
    for (int hd = 0; hd < 128; ++hd) {
        float wq = w_q[hd * 256 + c];
        #pragma unroll
        for (int o = 0; o < 16; ++o) wt[o] += ml[o][hd] * wq;
    }
    ushort* Abp = A16 + ((size_t)b * 256 + ot) * 256 + c;
    #pragma unroll
    for (int o = 0; o < 16; ++o) {
        Abp[(size_t)o * 256] = f2bf(wt[o] * sc);
        cbuf[c][o] = wt[o] * tc;
    }
    __syncthreads();
    {
        int o = t >> 4, seg = t & 15;
        float p = 0.f;
        #pragma unroll
        for (int i = 0; i < 16; ++i) p += cbuf[seg * 16 + i][o];
        pbuf[o][seg] = p;
    }
    __syncthreads();
    if (t < 16) {
        int o = t;
        float sum = 0.f;
        #pragma unroll
        for (int s2 = 0; s2 < 16; ++s2) sum += pbuf[o][s2];
        float md = 0.f;
        #pragma unroll 8
        for (int hd = 0; hd < 128; ++hd) md += ml[o][hd] * b_q[hd];
        biasb[(size_t)b * 256 + ot + o] = sum + md + b_out[ot + o];
    }
}

// ---------------------------------------------------------------------------
// L4: out = A16 @ x^T + bias.  BM=256, BN=128, BK=64; 8 waves (4x2), 512 thr.
// A and B reg-staged via NAMED regs with next-tile prefetch.
__global__ __launch_bounds__(512) void out_gemm_fused(const ushort* __restrict__ A16,
                                                      const float* __restrict__ x,
                                                      const float* __restrict__ biasb,
                                                      float* __restrict__ out) {
    __shared__ ushort lA[256 * 64];     // 32 KB
    __shared__ ushort lB[128 * 64];     // 16 KB
    __shared__ float scratch[64 * 128]; // 32 KB, granule-swizzled
    int b = blockIdx.y;
    int n0 = blockIdx.x * 128;
    int t = threadIdx.x;
    int l = t & 63, wid = t >> 6;
    int wr = wid >> 1, wc = wid & 1;          // 4 x 2 wave grid
    int lr = l & 15, lg = l >> 4;
    const ushort* Ab = A16 + (size_t)b * 65536;
    const float* xb = x + (size_t)b * 256 * 4096 + n0;
    int sp = t & 31, sj = t >> 5;             // c-pair (2sp,2sp+1), n-octet (16)
    uint4 a0_, a1_, a2_, a3_;
    float4 b0_, b1_, b2_, b3_;
    int rA = t >> 3, gA = (t & 7) ^ (rA & 7); // (64k+rA)&7 == rA&7
    int rB = t >> 5, gB = t & 31;
#define OG_LOADA(k0) { \
    a0_ = *(const uint4*)(Ab + (size_t)(rA)       * 256 + (k0) + gA * 8); \
    a1_ = *(const uint4*)(Ab + (size_t)(64 + rA)  * 256 + (k0) + gA * 8); \
    a2_ = *(const uint4*)(Ab + (size_t)(128 + rA) * 256 + (k0) + gA * 8); \
    a3_ = *(const uint4*)(Ab + (size_t)(192 + rA) * 256 + (k0) + gA * 8); }
#define OG_LOADB(k0) { \
    b0_ = *(const float4*)&xb[(size_t)((k0) + rB)      * 4096 + gB * 4]; \
    b1_ = *(const float4*)&xb[(size_t)((k0) + 16 + rB) * 4096 + gB * 4]; \
    b2_ = *(const float4*)&xb[(size_t)((k0) + 32 + rB) * 4096 + gB * 4]; \
    b3_ = *(const float4*)&xb[(size_t)((k0) + 48 + rB) * 4096 + gB * 4]; }
    OG_LOADA(0); OG_LOADB(0);
    f32x4 acc[4][4] = {};
    for (int it = 0; it < 4; ++it) {
        *(uint4*)((char*)lA + (size_t)t * 16)          = a0_;
        *(uint4*)((char*)lA + (size_t)(512 + t) * 16)  = a1_;
        *(uint4*)((char*)lA + (size_t)(1024 + t) * 16) = a2_;
        *(uint4*)((char*)lA + (size_t)(1536 + t) * 16) = a3_;
        *(float4*)((char*)scratch + (rB)      * 512 + (gB ^ (((rB)      >> 1) & 31)) * 16) = b0_;
        *(float4*)((char*)scratch + (16 + rB) * 512 + (gB ^ (((16 + rB) >> 1) & 31)) * 16) = b1_;
        *(float4*)((char*)scratch + (32 + rB) * 512 + (gB ^ (((32 + rB) >> 1) & 31)) * 16) = b2_;
        *(float4*)((char*)scratch + (48 + rB) * 512 + (gB ^ (((48 + rB) >> 1) & 31)) * 16) = b3_;
        __syncthreads();
        if (it < 3) { OG_LOADA(it * 64 + 64); OG_LOADB(it * 64 + 64); }   // prefetch
        {
            int swz = sp & 31;
            float4 s0 = *(const float4*)((char*)scratch + (2*sp)   * 512 + ((2*sj)   ^ swz) * 16);
            float4 s1 = *(const float4*)((char*)scratch + (2*sp)   * 512 + ((2*sj+1) ^ swz) * 16);
            float4 s2 = *(const float4*)((char*)scratch + (2*sp+1) * 512 + ((2*sj)   ^ swz) * 16);
            float4 s3 = *(const float4*)((char*)scratch + (2*sp+1) * 512 + ((2*sj+1) ^ swz) * 16);
            float c0v[8] = {s0.x, s0.y, s0.z, s0.w, s1.x, s1.y, s1.z, s1.w};
            float c1v[8] = {s2.x, s2.y, s2.z, s2.w, s3.x, s3.y, s3.z, s3.w};
            #pragma unroll
            for (int w = 0; w < 8; ++w) {
                int n = sj * 8 + w;
                unsigned pk = pack2(c0v[w], c1v[w]);
                *(unsigned*)((char*)lB + n * 128 + (((sp >> 2) ^ (n & 7)) * 16) + (sp & 3) * 4) = pk;
            }
        }
        __syncthreads();
        #pragma unroll
        for (int ks = 0; ks < 2; ++ks) {
            bf16x8 av[4], bv[4];
            #pragma unroll
            for (int mi = 0; mi < 4; ++mi) {
                int ar = wr * 64 + mi * 16 + lr;
                int q = (ks * 4 + lg) ^ (ar & 7);
                av[mi] = *(const bf16x8*)((const char*)lA + ar * 128 + q * 16);
            }
            #pragma unroll
            for (int ni = 0; ni < 4; ++ni) {
                int br = wc * 64 + ni * 16 + lr;
                int q = (ks * 4 + lg) ^ (br & 7);
                bv[ni] = *(const bf16x8*)((const char*)lB + br * 128 + q * 16);
            }
            #pragma unroll
            for (int mi = 0; mi < 4; ++mi)
                #pragma unroll
                for (int ni = 0; ni < 4; ++ni)
                    acc[mi][ni] = __builtin_amdgcn_mfma_f32_16x16x32_bf16(
                        av[mi], bv[ni], acc[mi][ni], 0, 0, 0);
        }
        __syncthreads();
    }
#undef OG_LOADA
#undef OG_LOADB
    const float* bp = biasb + (size_t)b * 256;
    int orow = wr * 64, ocol = n0 + wc * 64 + lr;
    #pragma unroll
    for (int mi = 0; mi < 4; ++mi) {
        int rb = orow + mi * 16 + lg * 4;
        float4 b4 = *(const float4*)&bp[rb];
        float bvr[4] = {b4.x, b4.y, b4.z, b4.w};
        #pragma unroll
        for (int ni = 0; ni < 4; ++ni) {
            int cc = ocol + ni * 16;
            #pragma unroll
            for (int r = 0; r < 4; ++r)
                out[((size_t)b * 256 + rb + r) * 4096 + cc] = acc[mi][ni][r] + bvr[r];
        }
    }
}

extern "C" void kernel_launch(void* const* d_in, const int* in_sizes, int n_in,
                              void* d_out, int out_size, void* d_ws, size_t ws_size,
                              hipStream_t stream) {
    const float* x     = (const float*)d_in[0];
    const float* cond  = (const float*)d_in[1];
    const float* gn_w  = (const float*)d_in[2];
    const float* gn_b  = (const float*)d_in[3];
    const float* w_q   = (const float*)d_in[4];
    const float* b_q   = (const float*)d_in[5];
    const float* w_kv  = (const float*)d_in[6];
    const float* b_kv  = (const float*)d_in[7];
    const float* w_out = (const float*)d_in[8];
    const float* b_out = (const float*)d_in[9];
    float* out = (float*)d_out;

    float* f       = (float*)d_ws;
    float* statacc = f;                     // 1024 floats (plain stores)
    float* rsp     = f + 1024;              // 16*32*128 = 65536 floats
    float* ctxp    = f + 66560;             // 16*32*4096 = 2097152 floats
    float* ctxn    = f + 2163712;           // 16*4096 = 65536 floats
    float* biasb   = f + 2229248;           // 4096 floats
    ushort* A16    = (ushort*)(f + 2233344);// 1048576 ushorts

    // L1: kv GEMM (BN=32, 512 blocks = 2/CU) + fused exp/PV + GN stats weave
    kvctx_kernel<<<512, 512, 0, stream>>>(w_kv, cond, b_kv, x, statacc, rsp, ctxp);
    // L2: reduce ctx/rowsum partials -> normalized ctxn (high parallelism)
    reduce_kernel<<<256, 256, 0, stream>>>(ctxp, rsp, ctxn);
    // L3: fold everything into per-batch A (bf16) + bias
    a_kernel<<<256, 256, 0, stream>>>(ctxn, w_out, w_q, b_q, statacc,
                                      gn_w, gn_b, b_out, A16, biasb);
    // L4: out = A @ x^T + bias
    out_gemm_fused<<<dim3(32, 16), 512, 0, stream>>>(A16, x, biasb, out);
}